// Round 10
// baseline (734.893 us; speedup 1.0000x reference)
//
#include <hip/hip_runtime.h>
#include <hip/hip_bf16.h>

// GAT layer, N=8192, DIN=256, DOUT=128.
// h = x@W+bW; e_ij = leaky_relu(s_src[i]+s_dst[j]+ba); p = adj ? exp(e) : 0
// out_i = (sum_j p_ij h_j)/(sum_j p_ij).
//
// R10 = R9 EXACTLY + INSTRUMENTATION: gat_attn takes a runtime `rep` count
// (host passes 2) and redoes its whole computation rep times (identical
// idempotent stores). Purpose: push the dispatch above the ~160us harness
// fill dispatches so it lands in rocprof top-5 WITH counters — gat_attn has
// been invisible since R5 and cross-round subtraction says it's ~120us while
// every pipe model says <=30us. True attn time = visible_dur / rep.

#define NN 8192
#define DIN 256
#define DOUT 128
#define LOG2E 1.4426950408889634f

typedef __attribute__((ext_vector_type(8))) short short8;   // 8 bf16 = 4 VGPRs (MFMA A/B frag)
typedef __attribute__((ext_vector_type(4))) float floatx4;  // MFMA C/D frag

// ---------------- kernel 0: W [256][128] fp32 -> WT [128][256] bf16 ----------------
__global__ void prep_wt(const float* __restrict__ W, __hip_bfloat16* __restrict__ WT) {
    int e = blockIdx.x * blockDim.x + threadIdx.x;
    if (e < DIN * DOUT) {
        int k = e >> 7;
        int d = e & 127;
        WT[d * DIN + k] = __float2bfloat16(W[e]);
    }
}

// ---------------- kernel 1: h = x@W + bW (MFMA), fused s_src/s_dst; h -> hbB frag-tile layout ----------------
// hbB flat index for h-element (row i, dim d):
//   g=i>>5, k=i&31, f=d>>4, n=d&15 -> g*4096 + f*512 + (k>>3)*128 + n*8 + (k&7)
__global__ __launch_bounds__(256, 4) void gat_h(
    const float* __restrict__ x, const __hip_bfloat16* __restrict__ WT,
    const float* __restrict__ bW, const float* __restrict__ a1, const float* __restrict__ a2,
    __hip_bfloat16* __restrict__ hbB, float* __restrict__ s_src, float* __restrict__ s_dst) {
    int tid = threadIdx.x;
    int w = tid >> 6, lane = tid & 63;
    int lm = lane & 15, lq = lane >> 4;
    int i0 = blockIdx.x * 32;
    int r0 = (w >> 1) * 16;
    int c0 = (w & 1) * 64;

    __shared__ float s1s[32], s2s[32];
    if (tid < 32) { s1s[tid] = 0.f; s2s[tid] = 0.f; }
    __syncthreads();

    floatx4 acc[4] = {};
#pragma unroll
    for (int kk = 0; kk < DIN; kk += 32) {
        const float4* xp = (const float4*)&x[(size_t)(i0 + r0 + lm) * DIN + kk + lq * 8];
        float4 xa = xp[0], xb = xp[1];
        union { short8 v; __hip_bfloat16 h[8]; } af;
        af.h[0] = __float2bfloat16(xa.x); af.h[1] = __float2bfloat16(xa.y);
        af.h[2] = __float2bfloat16(xa.z); af.h[3] = __float2bfloat16(xa.w);
        af.h[4] = __float2bfloat16(xb.x); af.h[5] = __float2bfloat16(xb.y);
        af.h[6] = __float2bfloat16(xb.z); af.h[7] = __float2bfloat16(xb.w);
#pragma unroll
        for (int t = 0; t < 4; t++) {
            int d = c0 + 16 * t + lm;
            short8 bf = *(const short8*)&WT[(size_t)d * DIN + kk + lq * 8];
            acc[t] = __builtin_amdgcn_mfma_f32_16x16x32_bf16(af.v, bf, acc[t], 0, 0, 0);
        }
    }
    float s1[4] = {0.f, 0.f, 0.f, 0.f}, s2[4] = {0.f, 0.f, 0.f, 0.f};
#pragma unroll
    for (int t = 0; t < 4; t++) {
        int d = c0 + 16 * t + lm;
        int f = (c0 >> 4) + t;
        float A1 = a1[d], A2 = a2[d], B = bW[d];
#pragma unroll
        for (int r = 0; r < 4; r++) {
            int k = r0 + lq * 4 + r;
            float h = acc[t][r] + B;
            hbB[(size_t)blockIdx.x * 4096 + f * 512 + (k >> 3) * 128 + lm * 8 + (k & 7)] =
                __float2bfloat16(h);
            s1[r] += h * A1;
            s2[r] += h * A2;
        }
    }
#pragma unroll
    for (int r = 0; r < 4; r++) {
        for (int m = 1; m < 16; m <<= 1) {
            s1[r] += __shfl_xor(s1[r], m, 64);
            s2[r] += __shfl_xor(s2[r], m, 64);
        }
    }
    if (lm == 0) {
#pragma unroll
        for (int r = 0; r < 4; r++) {
            int row = r0 + lq * 4 + r;
            atomicAdd(&s1s[row], s1[r]);
            atomicAdd(&s2s[row], s2[r]);
        }
    }
    __syncthreads();
    if (tid < 32) {
        s_src[i0 + tid] = s1s[tid] * LOG2E;   // pre-scale: exp(e) = exp2(e*log2e)
        s_dst[i0 + tid] = s2s[tid] * LOG2E;
    }
}

// ---------------- kernel 2: adj -> 1-bit mask, lane-permuted layout ----------------
template <int NJT>
__global__ void build_mask(const int* __restrict__ adj, unsigned char* __restrict__ mask) {
    size_t gid = (size_t)blockIdx.x * blockDim.x + threadIdx.x;  // 8,388,608 threads
    const int4* a = (const int4*)(adj + gid * 8);
    int4 v0 = a[0], v1 = a[1];
    unsigned int b = 0;
    b |= (v0.x != 0) ? 1u : 0u;
    b |= (v0.y != 0) ? 2u : 0u;
    b |= (v0.z != 0) ? 4u : 0u;
    b |= (v0.w != 0) ? 8u : 0u;
    b |= (v1.x != 0) ? 16u : 0u;
    b |= (v1.y != 0) ? 32u : 0u;
    b |= (v1.z != 0) ? 64u : 0u;
    b |= (v1.w != 0) ? 128u : 0u;
    unsigned int g = (unsigned int)gid & (NJT * 4 - 1);
    size_t pos = (gid & ~(size_t)(NJT * 4 - 1)) | ((g & 3) * NJT + (g >> 2));
    mask[pos] = (unsigned char)b;
}

__device__ inline short8 make_pfrag(unsigned int cm, float ssi, float4 cd0, float4 cd1,
                                    floatx4* accd, const short8 ones) {
    float p[8];
    float e;
    e = ssi + cd0.x; e = fmaxf(e, 0.01f * e); p[0] = (cm & 1u)   ? __builtin_amdgcn_exp2f(e) : 0.f;
    e = ssi + cd0.y; e = fmaxf(e, 0.01f * e); p[1] = (cm & 2u)   ? __builtin_amdgcn_exp2f(e) : 0.f;
    e = ssi + cd0.z; e = fmaxf(e, 0.01f * e); p[2] = (cm & 4u)   ? __builtin_amdgcn_exp2f(e) : 0.f;
    e = ssi + cd0.w; e = fmaxf(e, 0.01f * e); p[3] = (cm & 8u)   ? __builtin_amdgcn_exp2f(e) : 0.f;
    e = ssi + cd1.x; e = fmaxf(e, 0.01f * e); p[4] = (cm & 16u)  ? __builtin_amdgcn_exp2f(e) : 0.f;
    e = ssi + cd1.y; e = fmaxf(e, 0.01f * e); p[5] = (cm & 32u)  ? __builtin_amdgcn_exp2f(e) : 0.f;
    e = ssi + cd1.z; e = fmaxf(e, 0.01f * e); p[6] = (cm & 64u)  ? __builtin_amdgcn_exp2f(e) : 0.f;
    e = ssi + cd1.w; e = fmaxf(e, 0.01f * e); p[7] = (cm & 128u) ? __builtin_amdgcn_exp2f(e) : 0.f;
    union { short8 v; __hip_bfloat162 q[4]; } af;
    af.q[0] = __float22bfloat162_rn(make_float2(p[0], p[1]));
    af.q[1] = __float22bfloat162_rn(make_float2(p[2], p[3]));
    af.q[2] = __float22bfloat162_rn(make_float2(p[4], p[5]));
    af.q[3] = __float22bfloat162_rn(make_float2(p[6], p[7]));
    *accd = __builtin_amdgcn_mfma_f32_16x16x32_bf16(af.v, ones, *accd, 0, 0, 0);
    return af.v;
}

// ---------------- kernel 3: masked softmax-weighted GEMM (R9 structure + rep loop) ----------------
template <int NJT>
__global__ __launch_bounds__(256, 3) void gat_attn(
    const unsigned char* __restrict__ mask, const float* __restrict__ s_src,
    const float* __restrict__ s_dst, const float* __restrict__ ba_p,
    const __hip_bfloat16* __restrict__ hbB,
    float* __restrict__ num, float* __restrict__ lpart, int rep) {
    __shared__ float sdl[NJT * 32];
    int tid = threadIdx.x;
    int w = tid >> 6, lane = tid & 63;
    int lm = lane & 15, lq = lane >> 4;
    int b = blockIdx.x;
    int ib = b & 63;
    int jh = b >> 6;
    int i0 = ib * 128 + w * 32;
    int jb0 = jh * (NJT * 32);

    // stage this block's s_dst slice into LDS (one barrier total)
#pragma unroll
    for (int q = tid; q < NJT * 32; q += 256) sdl[q] = s_dst[jb0 + q];

    // per-lane mask slices for both row-groups: NJT contiguous bytes each
    const unsigned char* mrow0 = mask + (size_t)(i0 + lm) * (NN / 8) + jh * (NJT * 4) + lq * NJT;
    const unsigned char* mrow1 = mrow0 + (size_t)16 * (NN / 8);
    union Mr { uint4 v[NJT / 16]; unsigned int u[NJT / 4]; };
    Mr mr0, mr1;
#pragma unroll
    for (int q = 0; q < NJT / 16; q++) {
        mr0.v[q] = ((const uint4*)mrow0)[q];
        mr1.v[q] = ((const uint4*)mrow1)[q];
    }

    float ba = ba_p[0] * LOG2E;
    float ssi0 = s_src[i0 + lm] + ba;
    float ssi1 = s_src[i0 + 16 + lm] + ba;
    const __hip_bfloat16* hb = hbB + ((size_t)(jh * NJT) * 8) * 512 + lane * 8;
    const short8 ones = { 0x3F80, 0x3F80, 0x3F80, 0x3F80, 0x3F80, 0x3F80, 0x3F80, 0x3F80 };

    __syncthreads();

#pragma unroll 1
    for (int r_ = 0; r_ < rep; r_++) {   // INSTRUMENTATION: runtime trip count, host passes 2
        floatx4 acc0[8] = {}, acc1[8] = {};
        floatx4 accd0 = {}, accd1 = {};

#pragma unroll
        for (int t = 0; t < NJT; t++) {
            unsigned int cm0 = (mr0.u[t >> 2] >> ((t & 3) * 8)) & 0xFFu;
            unsigned int cm1 = (mr1.u[t >> 2] >> ((t & 3) * 8)) & 0xFFu;
            float4 cd0 = *(const float4*)&sdl[t * 32 + lq * 8];      // LDS: lgkmcnt, not vmcnt
            float4 cd1 = *(const float4*)&sdl[t * 32 + lq * 8 + 4];
            short8 af0 = make_pfrag(cm0, ssi0, cd0, cd1, &accd0, ones);
            short8 af1 = make_pfrag(cm1, ssi1, cd0, cd1, &accd1, ones);

            const __hip_bfloat16* hbt = hb + (size_t)t * 8 * 512;
#pragma unroll
            for (int f = 0; f < 8; f++) {
                short8 bf = *(const short8*)(hbt + f * 512);
                acc0[f] = __builtin_amdgcn_mfma_f32_16x16x32_bf16(af0, bf, acc0[f], 0, 0, 0);
                acc1[f] = __builtin_amdgcn_mfma_f32_16x16x32_bf16(af1, bf, acc1[f], 0, 0, 0);
            }
        }

        // epilogue: C/D layout col(dim-part)=lm, row=lq*4+r
        float* nb = num + ((size_t)jh * NN + i0) * DOUT;
#pragma unroll
        for (int f = 0; f < 8; f++)
#pragma unroll
            for (int r = 0; r < 4; r++) {
                nb[(size_t)(lq * 4 + r) * DOUT + f * 16 + lm] = acc0[f][r];
                nb[(size_t)(16 + lq * 4 + r) * DOUT + f * 16 + lm] = acc1[f][r];
            }
        if (lm == 0) {
#pragma unroll
            for (int r = 0; r < 4; r++) {
                lpart[(size_t)jh * NN + i0 + lq * 4 + r] = accd0[r];
                lpart[(size_t)jh * NN + i0 + 16 + lq * 4 + r] = accd1[r];
            }
        }
    }
}

// ---------------- kernel 4: combine partials, divide ----------------
__global__ void gat_combine(const float* __restrict__ num, const float* __restrict__ lpart,
                            float* __restrict__ out, int jsplit) {
    int gid = blockIdx.x * blockDim.x + threadIdx.x;  // 262144 threads, one float4 each
    int idx = gid * 4;
    int i = idx >> 7;
    float den = 0.f;
    for (int s = 0; s < jsplit; s++) den += lpart[(size_t)s * NN + i];
    float inv = 1.0f / den;
    float4 o = make_float4(0.f, 0.f, 0.f, 0.f);
    for (int s = 0; s < jsplit; s++) {
        float4 n = *(const float4*)&num[(size_t)s * NN * DOUT + idx];
        o.x += n.x; o.y += n.y; o.z += n.z; o.w += n.w;
    }
    o.x *= inv; o.y *= inv; o.z *= inv; o.w *= inv;
    *(float4*)&out[idx] = o;
}

extern "C" void kernel_launch(void* const* d_in, const int* in_sizes, int n_in,
                              void* d_out, int out_size, void* d_ws, size_t ws_size,
                              hipStream_t stream) {
    const float* x  = (const float*)d_in[0];
    const int* adj  = (const int*)d_in[1];
    const float* W  = (const float*)d_in[2];
    const float* bW = (const float*)d_in[3];
    const float* a1 = (const float*)d_in[4];
    const float* a2 = (const float*)d_in[5];
    const float* ba = (const float*)d_in[6];
    float* out = (float*)d_out;

    char* ws = (char*)d_ws;
    __hip_bfloat16* hbB  = (__hip_bfloat16*)ws;                    // 2 MB   frag-tile layout
    __hip_bfloat16* WT   = (__hip_bfloat16*)(ws + 2097152);        // 64 KB
    float* s_src         = (float*)(ws + 2162688);                 // 32 KB (pre-scaled by log2e)
    float* s_dst         = (float*)(ws + 2195456);                 // 32 KB (pre-scaled by log2e)
    float* lpart         = (float*)(ws + 2228224);                 // 512 KB [<=16][8192]
    unsigned char* mask  = (unsigned char*)(ws + 2752512);         // 8 MB   permuted
    float* num           = (float*)(ws + 11141120);                // jsplit*4 MB

    int jsplit = (ws_size >= 11141120 + (size_t)16 * NN * DOUT * 4) ? 16 : 8;

    if (jsplit == 16) build_mask<16><<<32768, 256, 0, stream>>>(adj, mask);
    else              build_mask<32><<<32768, 256, 0, stream>>>(adj, mask);
    prep_wt<<<128, 256, 0, stream>>>(W, WT);
    gat_h<<<256, 256, 0, stream>>>(x, WT, bW, a1, a2, hbB, s_src, s_dst);
    if (jsplit == 16)
        gat_attn<16><<<1024, 256, 0, stream>>>(mask, s_src, s_dst, ba, hbB, num, lpart, 2);
    else
        gat_attn<32><<<512, 256, 0, stream>>>(mask, s_src, s_dst, ba, hbB, num, lpart, 2);
    gat_combine<<<1024, 256, 0, stream>>>(num, lpart, out, jsplit);
}

// Round 11
// 555.660 us; speedup vs baseline: 1.3226x; 1.3226x over previous
//
#include <hip/hip_runtime.h>
#include <hip/hip_bf16.h>

// GAT layer, N=8192, DIN=256, DOUT=128.
// h = x@W+bW; e_ij = leaky_relu(s_src[i]+s_dst[j]+ba); p = adj ? exp(e) : 0
// out_i = (sum_j p_ij h_j)/(sum_j p_ij).
//
// R11: kill the HBM partials. R10's counters (rep=2): FETCH 523 + WRITE 578 MB
// at 3.1 TB/s -> gat_attn was HBM-BOUND on its own jsplit=16 `num` buffer
// (64 MB: write + RFO fetch + combine read) whose write stream also thrashed
// per-XCD L2, spilling the 128 MB B-frag demand to HBM. New structure:
// block = 4 waves x SAME 32 rows, each wave a different j-QUARTER; partials
// summed across waves in LDS (atomicAdd fp32, 16 KB), divide by denominator,
// write straight to out. num/lpart/gat_combine deleted. Attn traffic becomes
// mask 8 MB + hbB ~16 MB (L2-resident, nothing evicts it) + out 4 MB.

#define NN 8192
#define DIN 256
#define DOUT 128
#define LOG2E 1.4426950408889634f

typedef __attribute__((ext_vector_type(8))) short short8;   // 8 bf16 = 4 VGPRs (MFMA A/B frag)
typedef __attribute__((ext_vector_type(4))) float floatx4;  // MFMA C/D frag

// ---------------- kernel 0: W [256][128] fp32 -> WT [128][256] bf16 ----------------
__global__ void prep_wt(const float* __restrict__ W, __hip_bfloat16* __restrict__ WT) {
    int e = blockIdx.x * blockDim.x + threadIdx.x;
    if (e < DIN * DOUT) {
        int k = e >> 7;
        int d = e & 127;
        WT[d * DIN + k] = __float2bfloat16(W[e]);
    }
}

// ---------------- kernel 1: h = x@W + bW (MFMA), fused s_src/s_dst; h -> hbB frag-tile layout ----------------
// hbB flat index for h-element (row i, dim d):
//   g=i>>5, k=i&31, f=d>>4, n=d&15 -> g*4096 + f*512 + (k>>3)*128 + n*8 + (k&7)
__global__ __launch_bounds__(256, 4) void gat_h(
    const float* __restrict__ x, const __hip_bfloat16* __restrict__ WT,
    const float* __restrict__ bW, const float* __restrict__ a1, const float* __restrict__ a2,
    __hip_bfloat16* __restrict__ hbB, float* __restrict__ s_src, float* __restrict__ s_dst) {
    int tid = threadIdx.x;
    int w = tid >> 6, lane = tid & 63;
    int lm = lane & 15, lq = lane >> 4;
    int i0 = blockIdx.x * 32;
    int r0 = (w >> 1) * 16;
    int c0 = (w & 1) * 64;

    __shared__ float s1s[32], s2s[32];
    if (tid < 32) { s1s[tid] = 0.f; s2s[tid] = 0.f; }
    __syncthreads();

    floatx4 acc[4] = {};
#pragma unroll
    for (int kk = 0; kk < DIN; kk += 32) {
        const float4* xp = (const float4*)&x[(size_t)(i0 + r0 + lm) * DIN + kk + lq * 8];
        float4 xa = xp[0], xb = xp[1];
        union { short8 v; __hip_bfloat16 h[8]; } af;
        af.h[0] = __float2bfloat16(xa.x); af.h[1] = __float2bfloat16(xa.y);
        af.h[2] = __float2bfloat16(xa.z); af.h[3] = __float2bfloat16(xa.w);
        af.h[4] = __float2bfloat16(xb.x); af.h[5] = __float2bfloat16(xb.y);
        af.h[6] = __float2bfloat16(xb.z); af.h[7] = __float2bfloat16(xb.w);
#pragma unroll
        for (int t = 0; t < 4; t++) {
            int d = c0 + 16 * t + lm;
            short8 bf = *(const short8*)&WT[(size_t)d * DIN + kk + lq * 8];
            acc[t] = __builtin_amdgcn_mfma_f32_16x16x32_bf16(af.v, bf, acc[t], 0, 0, 0);
        }
    }
    float s1[4] = {0.f, 0.f, 0.f, 0.f}, s2[4] = {0.f, 0.f, 0.f, 0.f};
#pragma unroll
    for (int t = 0; t < 4; t++) {
        int d = c0 + 16 * t + lm;
        int f = (c0 >> 4) + t;
        float A1 = a1[d], A2 = a2[d], B = bW[d];
#pragma unroll
        for (int r = 0; r < 4; r++) {
            int k = r0 + lq * 4 + r;
            float h = acc[t][r] + B;
            hbB[(size_t)blockIdx.x * 4096 + f * 512 + (k >> 3) * 128 + lm * 8 + (k & 7)] =
                __float2bfloat16(h);
            s1[r] += h * A1;
            s2[r] += h * A2;
        }
    }
#pragma unroll
    for (int r = 0; r < 4; r++) {
        for (int m = 1; m < 16; m <<= 1) {
            s1[r] += __shfl_xor(s1[r], m, 64);
            s2[r] += __shfl_xor(s2[r], m, 64);
        }
    }
    if (lm == 0) {
#pragma unroll
        for (int r = 0; r < 4; r++) {
            int row = r0 + lq * 4 + r;
            atomicAdd(&s1s[row], s1[r]);
            atomicAdd(&s2s[row], s2[r]);
        }
    }
    __syncthreads();
    if (tid < 32) {
        s_src[i0 + tid] = s1s[tid] * LOG2E;   // pre-scale: exp(e) = exp2(e*log2e)
        s_dst[i0 + tid] = s2s[tid] * LOG2E;
    }
}

// ---------------- kernel 2: adj -> 1-bit mask, lane-permuted (chunk=256 groups) ----------------
// Within each 256-byte-group chunk (one j-quarter of a row), group gg is stored
// at (gg&3)*64 + (gg>>2), so consumer lane (lq) finds its 64 bytes contiguous.
__global__ void build_mask(const int* __restrict__ adj, unsigned char* __restrict__ mask) {
    size_t gid = (size_t)blockIdx.x * blockDim.x + threadIdx.x;  // 8,388,608 threads
    const int4* a = (const int4*)(adj + gid * 8);
    int4 v0 = a[0], v1 = a[1];
    unsigned int b = 0;
    b |= (v0.x != 0) ? 1u : 0u;
    b |= (v0.y != 0) ? 2u : 0u;
    b |= (v0.z != 0) ? 4u : 0u;
    b |= (v0.w != 0) ? 8u : 0u;
    b |= (v1.x != 0) ? 16u : 0u;
    b |= (v1.y != 0) ? 32u : 0u;
    b |= (v1.z != 0) ? 64u : 0u;
    b |= (v1.w != 0) ? 128u : 0u;
    unsigned int g = (unsigned int)gid & 255u;
    size_t pos = (gid & ~(size_t)255) | ((g & 3u) * 64u + (g >> 2));
    mask[pos] = (unsigned char)b;
}

__device__ inline short8 make_pfrag(unsigned int cm, float ssi, float4 cd0, float4 cd1,
                                    floatx4* accd, const short8 ones) {
    float p[8];
    float e;
    e = ssi + cd0.x; e = fmaxf(e, 0.01f * e); p[0] = (cm & 1u)   ? __builtin_amdgcn_exp2f(e) : 0.f;
    e = ssi + cd0.y; e = fmaxf(e, 0.01f * e); p[1] = (cm & 2u)   ? __builtin_amdgcn_exp2f(e) : 0.f;
    e = ssi + cd0.z; e = fmaxf(e, 0.01f * e); p[2] = (cm & 4u)   ? __builtin_amdgcn_exp2f(e) : 0.f;
    e = ssi + cd0.w; e = fmaxf(e, 0.01f * e); p[3] = (cm & 8u)   ? __builtin_amdgcn_exp2f(e) : 0.f;
    e = ssi + cd1.x; e = fmaxf(e, 0.01f * e); p[4] = (cm & 16u)  ? __builtin_amdgcn_exp2f(e) : 0.f;
    e = ssi + cd1.y; e = fmaxf(e, 0.01f * e); p[5] = (cm & 32u)  ? __builtin_amdgcn_exp2f(e) : 0.f;
    e = ssi + cd1.z; e = fmaxf(e, 0.01f * e); p[6] = (cm & 64u)  ? __builtin_amdgcn_exp2f(e) : 0.f;
    e = ssi + cd1.w; e = fmaxf(e, 0.01f * e); p[7] = (cm & 128u) ? __builtin_amdgcn_exp2f(e) : 0.f;
    union { short8 v; __hip_bfloat162 q[4]; } af;
    af.q[0] = __float22bfloat162_rn(make_float2(p[0], p[1]));
    af.q[1] = __float22bfloat162_rn(make_float2(p[2], p[3]));
    af.q[2] = __float22bfloat162_rn(make_float2(p[4], p[5]));
    af.q[3] = __float22bfloat162_rn(make_float2(p[6], p[7]));
    *accd = __builtin_amdgcn_mfma_f32_16x16x32_bf16(af.v, ones, *accd, 0, 0, 0);
    return af.v;
}

// ---------------- kernel 3: attention, j-split ACROSS WAVES, LDS cross-wave reduce ----------------
// grid = 256 blocks x 256 thr. Block owns rows i0=blockIdx*32 .. +31; wave w
// handles j-quarter [w*2048, (w+1)*2048) = 64 tiles of 32. Partials combined
// in LDS (atomicAdd fp32), divided by the denominator, written straight to out.
__global__ __launch_bounds__(256, 1) void gat_attn(
    const unsigned char* __restrict__ mask, const float* __restrict__ s_src,
    const float* __restrict__ s_dst, const float* __restrict__ ba_p,
    const __hip_bfloat16* __restrict__ hbB, float* __restrict__ out) {
    __shared__ float red[32][128];   // 16 KB numerator accumulator
    __shared__ float den[32];
    int tid = threadIdx.x;
    int w = tid >> 6, lane = tid & 63;
    int lm = lane & 15, lq = lane >> 4;
    int i0 = blockIdx.x * 32;

    // zero the reduction buffers
    for (int q = tid; q < 32 * 128; q += 256) ((float*)red)[q] = 0.f;
    if (tid < 32) den[tid] = 0.f;

    // per-lane mask slices: 64 contiguous bytes per rowgroup (permuted layout)
    const unsigned char* mrow0 = mask + (size_t)(i0 + lm) * (NN / 8) + w * 256 + lq * 64;
    const unsigned char* mrow1 = mrow0 + (size_t)16 * (NN / 8);
    union Mr { uint4 v[4]; unsigned int u[16]; };
    Mr mr0, mr1;
#pragma unroll
    for (int q = 0; q < 4; q++) {
        mr0.v[q] = ((const uint4*)mrow0)[q];
        mr1.v[q] = ((const uint4*)mrow1)[q];
    }

    float ba = ba_p[0] * LOG2E;
    float ssi0 = s_src[i0 + lm] + ba;
    float ssi1 = s_src[i0 + 16 + lm] + ba;
    const float* sd = s_dst + w * 2048 + lq * 8;
    const __hip_bfloat16* hb = hbB + (size_t)(w * 64) * 4096 + lane * 8;

    floatx4 acc0[8] = {}, acc1[8] = {};
    floatx4 accd0 = {}, accd1 = {};
    const short8 ones = { 0x3F80, 0x3F80, 0x3F80, 0x3F80, 0x3F80, 0x3F80, 0x3F80, 0x3F80 };

    __syncthreads();   // covers the zero-init (atomics happen after the loop)

#pragma unroll 4
    for (int t = 0; t < 64; t++) {
        unsigned int cm0 = (mr0.u[t >> 2] >> ((t & 3) * 8)) & 0xFFu;
        unsigned int cm1 = (mr1.u[t >> 2] >> ((t & 3) * 8)) & 0xFFu;
        float4 cd0 = *(const float4*)(sd + t * 32);
        float4 cd1 = *(const float4*)(sd + t * 32 + 4);
        short8 af0 = make_pfrag(cm0, ssi0, cd0, cd1, &accd0, ones);
        short8 af1 = make_pfrag(cm1, ssi1, cd0, cd1, &accd1, ones);

        const __hip_bfloat16* hbt = hb + (size_t)t * 4096;
#pragma unroll
        for (int f = 0; f < 8; f++) {
            short8 bf = *(const short8*)(hbt + f * 512);
            acc0[f] = __builtin_amdgcn_mfma_f32_16x16x32_bf16(af0, bf, acc0[f], 0, 0, 0);
            acc1[f] = __builtin_amdgcn_mfma_f32_16x16x32_bf16(af1, bf, acc1[f], 0, 0, 0);
        }
    }

    // cross-wave reduce in LDS. C/D layout: col(dim)=lm, row=lq*4+r.
#pragma unroll
    for (int f = 0; f < 8; f++)
#pragma unroll
        for (int r = 0; r < 4; r++) {
            atomicAdd(&red[lq * 4 + r][f * 16 + lm], acc0[f][r]);
            atomicAdd(&red[16 + lq * 4 + r][f * 16 + lm], acc1[f][r]);
        }
    if (lm == 0) {
#pragma unroll
        for (int r = 0; r < 4; r++) {
            atomicAdd(&den[lq * 4 + r], accd0[r]);
            atomicAdd(&den[16 + lq * 4 + r], accd1[r]);
        }
    }
    __syncthreads();

    // divide + store: thread q -> row q>>3, cols (q&7)*16 .. +15
    int row = tid >> 3, cb = (tid & 7) * 16;
    float inv = 1.0f / den[row];
    float* op = out + (size_t)(i0 + row) * DOUT + cb;
#pragma unroll
    for (int c = 0; c < 4; c++) {
        float4 v = *(const float4*)&red[row][cb + c * 4];
        v.x *= inv; v.y *= inv; v.z *= inv; v.w *= inv;
        *(float4*)(op + c * 4) = v;
    }
}

extern "C" void kernel_launch(void* const* d_in, const int* in_sizes, int n_in,
                              void* d_out, int out_size, void* d_ws, size_t ws_size,
                              hipStream_t stream) {
    const float* x  = (const float*)d_in[0];
    const int* adj  = (const int*)d_in[1];
    const float* W  = (const float*)d_in[2];
    const float* bW = (const float*)d_in[3];
    const float* a1 = (const float*)d_in[4];
    const float* a2 = (const float*)d_in[5];
    const float* ba = (const float*)d_in[6];
    float* out = (float*)d_out;

    char* ws = (char*)d_ws;
    __hip_bfloat16* hbB  = (__hip_bfloat16*)ws;                    // 2 MB   frag-tile layout
    __hip_bfloat16* WT   = (__hip_bfloat16*)(ws + 2097152);        // 64 KB
    float* s_src         = (float*)(ws + 2162688);                 // 32 KB (pre-scaled by log2e)
    float* s_dst         = (float*)(ws + 2195456);                 // 32 KB (pre-scaled by log2e)
    unsigned char* mask  = (unsigned char*)(ws + 2228224);         // 8 MB   permuted

    // build_mask first: keeps gat_h's outputs L2-warm for gat_attn.
    build_mask<<<32768, 256, 0, stream>>>(adj, mask);
    prep_wt<<<128, 256, 0, stream>>>(W, WT);
    gat_h<<<256, 256, 0, stream>>>(x, WT, bW, a1, a2, hbB, s_src, s_dst);
    gat_attn<<<256, 256, 0, stream>>>(mask, s_src, s_dst, ba, hbB, out);
}

// Round 12
// 500.777 us; speedup vs baseline: 1.4675x; 1.1096x over previous
//
#include <hip/hip_runtime.h>
#include <hip/hip_bf16.h>

// GAT layer, N=8192, DIN=256, DOUT=128.
// h = x@W+bW; e_ij = leaky_relu(s_src[i]+s_dst[j]+ba); p = adj ? exp(e) : 0
// out_i = (sum_j p_ij h_j)/(sum_j p_ij).
//
// R12 = R11 algorithm (LDS cross-wave reduce, no HBM partials: FETCH 16 MB
// verified) with the occupancy defect fixed. R11 ran 1 block/CU = 1 wave/SIMD
// (Occupancy 11%) -> every L2 latency exposed -> 184us. Now: 512-thread
// blocks, 8 waves sharing the SAME 32 rows, each wave a j-EIGHTH (32 tiles,
// I=32 B-reuse kept). launch_bounds(512,4) caps VGPR at 128 -> 4 waves/SIMD
// = 2 blocks/CU = 16 waves/CU. red[] stride padded 128->132 (R11 measured
// 49k LDS bank conflicts from the 512-float row stride: 4 lq-groups/bank).

#define NN 8192
#define DIN 256
#define DOUT 128
#define LOG2E 1.4426950408889634f

typedef __attribute__((ext_vector_type(8))) short short8;   // 8 bf16 = 4 VGPRs (MFMA A/B frag)
typedef __attribute__((ext_vector_type(4))) float floatx4;  // MFMA C/D frag

// ---------------- kernel 0: W [256][128] fp32 -> WT [128][256] bf16 ----------------
__global__ void prep_wt(const float* __restrict__ W, __hip_bfloat16* __restrict__ WT) {
    int e = blockIdx.x * blockDim.x + threadIdx.x;
    if (e < DIN * DOUT) {
        int k = e >> 7;
        int d = e & 127;
        WT[d * DIN + k] = __float2bfloat16(W[e]);
    }
}

// ---------------- kernel 1: h = x@W + bW (MFMA), fused s_src/s_dst; h -> hbB frag-tile layout ----------------
// hbB flat index for h-element (row i, dim d):
//   g=i>>5, k=i&31, f=d>>4, n=d&15 -> g*4096 + f*512 + (k>>3)*128 + n*8 + (k&7)
__global__ __launch_bounds__(256, 4) void gat_h(
    const float* __restrict__ x, const __hip_bfloat16* __restrict__ WT,
    const float* __restrict__ bW, const float* __restrict__ a1, const float* __restrict__ a2,
    __hip_bfloat16* __restrict__ hbB, float* __restrict__ s_src, float* __restrict__ s_dst) {
    int tid = threadIdx.x;
    int w = tid >> 6, lane = tid & 63;
    int lm = lane & 15, lq = lane >> 4;
    int i0 = blockIdx.x * 32;
    int r0 = (w >> 1) * 16;
    int c0 = (w & 1) * 64;

    __shared__ float s1s[32], s2s[32];
    if (tid < 32) { s1s[tid] = 0.f; s2s[tid] = 0.f; }
    __syncthreads();

    floatx4 acc[4] = {};
#pragma unroll
    for (int kk = 0; kk < DIN; kk += 32) {
        const float4* xp = (const float4*)&x[(size_t)(i0 + r0 + lm) * DIN + kk + lq * 8];
        float4 xa = xp[0], xb = xp[1];
        union { short8 v; __hip_bfloat16 h[8]; } af;
        af.h[0] = __float2bfloat16(xa.x); af.h[1] = __float2bfloat16(xa.y);
        af.h[2] = __float2bfloat16(xa.z); af.h[3] = __float2bfloat16(xa.w);
        af.h[4] = __float2bfloat16(xb.x); af.h[5] = __float2bfloat16(xb.y);
        af.h[6] = __float2bfloat16(xb.z); af.h[7] = __float2bfloat16(xb.w);
#pragma unroll
        for (int t = 0; t < 4; t++) {
            int d = c0 + 16 * t + lm;
            short8 bf = *(const short8*)&WT[(size_t)d * DIN + kk + lq * 8];
            acc[t] = __builtin_amdgcn_mfma_f32_16x16x32_bf16(af.v, bf, acc[t], 0, 0, 0);
        }
    }
    float s1[4] = {0.f, 0.f, 0.f, 0.f}, s2[4] = {0.f, 0.f, 0.f, 0.f};
#pragma unroll
    for (int t = 0; t < 4; t++) {
        int d = c0 + 16 * t + lm;
        int f = (c0 >> 4) + t;
        float A1 = a1[d], A2 = a2[d], B = bW[d];
#pragma unroll
        for (int r = 0; r < 4; r++) {
            int k = r0 + lq * 4 + r;
            float h = acc[t][r] + B;
            hbB[(size_t)blockIdx.x * 4096 + f * 512 + (k >> 3) * 128 + lm * 8 + (k & 7)] =
                __float2bfloat16(h);
            s1[r] += h * A1;
            s2[r] += h * A2;
        }
    }
#pragma unroll
    for (int r = 0; r < 4; r++) {
        for (int m = 1; m < 16; m <<= 1) {
            s1[r] += __shfl_xor(s1[r], m, 64);
            s2[r] += __shfl_xor(s2[r], m, 64);
        }
    }
    if (lm == 0) {
#pragma unroll
        for (int r = 0; r < 4; r++) {
            int row = r0 + lq * 4 + r;
            atomicAdd(&s1s[row], s1[r]);
            atomicAdd(&s2s[row], s2[r]);
        }
    }
    __syncthreads();
    if (tid < 32) {
        s_src[i0 + tid] = s1s[tid] * LOG2E;   // pre-scale: exp(e) = exp2(e*log2e)
        s_dst[i0 + tid] = s2s[tid] * LOG2E;
    }
}

// ---------------- kernel 2: adj -> 1-bit mask, lane-permuted (chunk=128 groups) ----------------
// Within each 128-byte-group chunk (one j-eighth of a row), group g=(t*4+lq)
// is stored at lq*32 + t, so consumer lane (lq) finds its 32 bytes contiguous.
__global__ void build_mask(const int* __restrict__ adj, unsigned char* __restrict__ mask) {
    size_t gid = (size_t)blockIdx.x * blockDim.x + threadIdx.x;  // 8,388,608 threads
    const int4* a = (const int4*)(adj + gid * 8);
    int4 v0 = a[0], v1 = a[1];
    unsigned int b = 0;
    b |= (v0.x != 0) ? 1u : 0u;
    b |= (v0.y != 0) ? 2u : 0u;
    b |= (v0.z != 0) ? 4u : 0u;
    b |= (v0.w != 0) ? 8u : 0u;
    b |= (v1.x != 0) ? 16u : 0u;
    b |= (v1.y != 0) ? 32u : 0u;
    b |= (v1.z != 0) ? 64u : 0u;
    b |= (v1.w != 0) ? 128u : 0u;
    unsigned int g = (unsigned int)gid & 127u;
    size_t pos = (gid & ~(size_t)127) | ((g & 3u) * 32u + (g >> 2));
    mask[pos] = (unsigned char)b;
}

__device__ inline short8 make_pfrag(unsigned int cm, float ssi, float4 cd0, float4 cd1,
                                    floatx4* accd, const short8 ones) {
    float p[8];
    float e;
    e = ssi + cd0.x; e = fmaxf(e, 0.01f * e); p[0] = (cm & 1u)   ? __builtin_amdgcn_exp2f(e) : 0.f;
    e = ssi + cd0.y; e = fmaxf(e, 0.01f * e); p[1] = (cm & 2u)   ? __builtin_amdgcn_exp2f(e) : 0.f;
    e = ssi + cd0.z; e = fmaxf(e, 0.01f * e); p[2] = (cm & 4u)   ? __builtin_amdgcn_exp2f(e) : 0.f;
    e = ssi + cd0.w; e = fmaxf(e, 0.01f * e); p[3] = (cm & 8u)   ? __builtin_amdgcn_exp2f(e) : 0.f;
    e = ssi + cd1.x; e = fmaxf(e, 0.01f * e); p[4] = (cm & 16u)  ? __builtin_amdgcn_exp2f(e) : 0.f;
    e = ssi + cd1.y; e = fmaxf(e, 0.01f * e); p[5] = (cm & 32u)  ? __builtin_amdgcn_exp2f(e) : 0.f;
    e = ssi + cd1.z; e = fmaxf(e, 0.01f * e); p[6] = (cm & 64u)  ? __builtin_amdgcn_exp2f(e) : 0.f;
    e = ssi + cd1.w; e = fmaxf(e, 0.01f * e); p[7] = (cm & 128u) ? __builtin_amdgcn_exp2f(e) : 0.f;
    union { short8 v; __hip_bfloat162 q[4]; } af;
    af.q[0] = __float22bfloat162_rn(make_float2(p[0], p[1]));
    af.q[1] = __float22bfloat162_rn(make_float2(p[2], p[3]));
    af.q[2] = __float22bfloat162_rn(make_float2(p[4], p[5]));
    af.q[3] = __float22bfloat162_rn(make_float2(p[6], p[7]));
    *accd = __builtin_amdgcn_mfma_f32_16x16x32_bf16(af.v, ones, *accd, 0, 0, 0);
    return af.v;
}

// ---------------- kernel 3: attention, 8 waves x j-eighths, LDS cross-wave reduce ----------------
// grid = 256 blocks x 512 thr. Block owns rows i0=blockIdx*32 .. +31; wave w
// handles j-eighth [w*1024, (w+1)*1024) = 32 tiles of 32. Partials combined
// in LDS, divided by denominator, written straight to out.
__global__ __launch_bounds__(512, 4) void gat_attn(
    const unsigned char* __restrict__ mask, const float* __restrict__ s_src,
    const float* __restrict__ s_dst, const float* __restrict__ ba_p,
    const __hip_bfloat16* __restrict__ hbB, float* __restrict__ out) {
    __shared__ float red[32][132];   // padded stride: kills 4-way atomic bank conflicts
    __shared__ float den[32];
    int tid = threadIdx.x;
    int w = tid >> 6, lane = tid & 63;
    int lm = lane & 15, lq = lane >> 4;
    int i0 = blockIdx.x * 32;

    // zero the reduction buffers
    for (int q = tid; q < 32 * 132; q += 512) ((float*)red)[q] = 0.f;
    if (tid < 32) den[tid] = 0.f;

    // per-lane mask slices: 32 contiguous bytes per rowgroup (permuted layout)
    const unsigned char* mrow0 = mask + (size_t)(i0 + lm) * (NN / 8) + w * 128 + lq * 32;
    const unsigned char* mrow1 = mrow0 + (size_t)16 * (NN / 8);
    union Mr { uint4 v[2]; unsigned int u[8]; };
    Mr mr0, mr1;
#pragma unroll
    for (int q = 0; q < 2; q++) {
        mr0.v[q] = ((const uint4*)mrow0)[q];
        mr1.v[q] = ((const uint4*)mrow1)[q];
    }

    float ba = ba_p[0] * LOG2E;
    float ssi0 = s_src[i0 + lm] + ba;
    float ssi1 = s_src[i0 + 16 + lm] + ba;
    const float* sd = s_dst + w * 1024 + lq * 8;
    const __hip_bfloat16* hb = hbB + (size_t)(w * 32) * 4096 + lane * 8;

    floatx4 acc0[8] = {}, acc1[8] = {};
    floatx4 accd0 = {}, accd1 = {};
    const short8 ones = { 0x3F80, 0x3F80, 0x3F80, 0x3F80, 0x3F80, 0x3F80, 0x3F80, 0x3F80 };

    __syncthreads();   // covers the zero-init (atomics happen after the loop)

#pragma unroll 4
    for (int t = 0; t < 32; t++) {
        unsigned int cm0 = (mr0.u[t >> 2] >> ((t & 3) * 8)) & 0xFFu;
        unsigned int cm1 = (mr1.u[t >> 2] >> ((t & 3) * 8)) & 0xFFu;
        float4 cd0 = *(const float4*)(sd + t * 32);
        float4 cd1 = *(const float4*)(sd + t * 32 + 4);
        short8 af0 = make_pfrag(cm0, ssi0, cd0, cd1, &accd0, ones);
        short8 af1 = make_pfrag(cm1, ssi1, cd0, cd1, &accd1, ones);

        const __hip_bfloat16* hbt = hb + (size_t)t * 4096;
#pragma unroll
        for (int f = 0; f < 8; f++) {
            short8 bf = *(const short8*)(hbt + f * 512);
            acc0[f] = __builtin_amdgcn_mfma_f32_16x16x32_bf16(af0, bf, acc0[f], 0, 0, 0);
            acc1[f] = __builtin_amdgcn_mfma_f32_16x16x32_bf16(af1, bf, acc1[f], 0, 0, 0);
        }
    }

    // cross-wave reduce in LDS. C/D layout: col(dim)=lm, row=lq*4+r.
#pragma unroll
    for (int f = 0; f < 8; f++)
#pragma unroll
        for (int r = 0; r < 4; r++) {
            atomicAdd(&red[lq * 4 + r][f * 16 + lm], acc0[f][r]);
            atomicAdd(&red[16 + lq * 4 + r][f * 16 + lm], acc1[f][r]);
        }
    if (lm == 0) {
#pragma unroll
        for (int r = 0; r < 4; r++) {
            atomicAdd(&den[lq * 4 + r], accd0[r]);
            atomicAdd(&den[16 + lq * 4 + r], accd1[r]);
        }
    }
    __syncthreads();

    // divide + store: thread q -> row q>>4, cols (q&15)*8 .. +7
    int row = tid >> 4, cb = (tid & 15) * 8;
    float inv = 1.0f / den[row];
    float* op = out + (size_t)(i0 + row) * DOUT + cb;
#pragma unroll
    for (int c = 0; c < 2; c++) {
        float4 v = *(const float4*)&red[row][cb + c * 4];
        v.x *= inv; v.y *= inv; v.z *= inv; v.w *= inv;
        *(float4*)(op + c * 4) = v;
    }
}

extern "C" void kernel_launch(void* const* d_in, const int* in_sizes, int n_in,
                              void* d_out, int out_size, void* d_ws, size_t ws_size,
                              hipStream_t stream) {
    const float* x  = (const float*)d_in[0];
    const int* adj  = (const int*)d_in[1];
    const float* W  = (const float*)d_in[2];
    const float* bW = (const float*)d_in[3];
    const float* a1 = (const float*)d_in[4];
    const float* a2 = (const float*)d_in[5];
    const float* ba = (const float*)d_in[6];
    float* out = (float*)d_out;

    char* ws = (char*)d_ws;
    __hip_bfloat16* hbB  = (__hip_bfloat16*)ws;                    // 2 MB   frag-tile layout
    __hip_bfloat16* WT   = (__hip_bfloat16*)(ws + 2097152);        // 64 KB
    float* s_src         = (float*)(ws + 2162688);                 // 32 KB (pre-scaled by log2e)
    float* s_dst         = (float*)(ws + 2195456);                 // 32 KB (pre-scaled by log2e)
    unsigned char* mask  = (unsigned char*)(ws + 2228224);         // 8 MB   permuted

    // build_mask first: keeps gat_h's outputs L2-warm for gat_attn.
    build_mask<<<32768, 256, 0, stream>>>(adj, mask);
    prep_wt<<<128, 256, 0, stream>>>(W, WT);
    gat_h<<<256, 256, 0, stream>>>(x, WT, bW, a1, a2, hbB, s_src, s_dst);
    gat_attn<<<256, 512, 0, stream>>>(mask, s_src, s_dst, ba, hbB, out);
}